// Round 13
// baseline (338.820 us; speedup 1.0000x reference)
//
#include <hip/hip_runtime.h>
#include <hip/hip_bf16.h>
#include <math.h>

// Problem constants
#define BATCH 4
#define SEQ   2048
#define HID   768
#define INTER 1536
#define DK    128
#define NTOT  3200      // 2*INTER + DK
#define MROWS 8192      // BATCH*SEQ
#define LN512 6.2383246250395075f

typedef _Float16 half8  __attribute__((ext_vector_type(8)));
typedef float    floatx4 __attribute__((ext_vector_type(4)));

typedef const __attribute__((address_space(1))) unsigned int* gas1_t;
typedef __attribute__((address_space(3))) unsigned int* las3_t;

static __device__ __forceinline__ void load16(const _Float16* g, _Float16* l) {
    __builtin_amdgcn_global_load_lds((gas1_t)g, (las3_t)l, 16, 0, 0);
}
// Compiler-opaque barriers/waits: memory clobber pins IR ordering;
// hardware waits only the stated counts.
#define WAIT_VM(N)    asm volatile("s_waitcnt vmcnt(" #N ")" ::: "memory")
#define WAIT_LGKM0()  asm volatile("s_waitcnt lgkmcnt(0)" ::: "memory")
#define BARRIER_RAW() asm volatile("s_barrier" ::: "memory")

// ---------------------------------------------------------------- prep kernels
__global__ void cast_h_kernel(const float* __restrict__ in, _Float16* __restrict__ out, int n) {
    int i = (blockIdx.x * blockDim.x + threadIdx.x) * 8;
    if (i < n) {
        float4 a = *reinterpret_cast<const float4*>(in + i);
        float4 b = *reinterpret_cast<const float4*>(in + i + 4);
        half8 h = {(_Float16)a.x, (_Float16)a.y, (_Float16)a.z, (_Float16)a.w,
                   (_Float16)b.x, (_Float16)b.y, (_Float16)b.z, (_Float16)b.w};
        *reinterpret_cast<half8*>(out + i) = h;
    }
}

// 32x32 LDS tile transpose, coalesced read + write.  WiT[c][r] = Wi[r][c]
__global__ void trans_wi_kernel(const float* __restrict__ Wi, _Float16* __restrict__ WiT) {
    __shared__ _Float16 tile[32][33];
    const int c0 = blockIdx.x * 32, r0 = blockIdx.y * 32;
    const int tx = threadIdx.x, ty = threadIdx.y;
#pragma unroll
    for (int j = 0; j < 32; j += 8)
        tile[tx][ty + j] = (_Float16)Wi[(size_t)(r0 + ty + j) * NTOT + c0 + tx];
    __syncthreads();
#pragma unroll
    for (int j = 0; j < 32; j += 8)
        WiT[(size_t)(c0 + ty + j) * HID + r0 + tx] = tile[ty + j][tx];
}

__global__ void trans_wo_kernel(const float* __restrict__ Wo, _Float16* __restrict__ WoT) {
    __shared__ _Float16 tile[32][33];
    const int c0 = blockIdx.x * 32, r0 = blockIdx.y * 32;
    const int tx = threadIdx.x, ty = threadIdx.y;
#pragma unroll
    for (int j = 0; j < 32; j += 8)
        tile[tx][ty + j] = (_Float16)Wo[(size_t)(r0 + ty + j) * HID + c0 + tx];
    __syncthreads();
#pragma unroll
    for (int j = 0; j < 32; j += 8)
        WoT[(size_t)(c0 + ty + j) * INTER + r0 + tx] = tile[ty + j][tx];
}

__global__ void mask_scales_kernel(const int* __restrict__ mask, float* __restrict__ scales) {
    __shared__ int sh[256];
    int b = blockIdx.x;
    int s = 0;
    for (int i = threadIdx.x; i < SEQ; i += 256) s += mask[b * SEQ + i];
    sh[threadIdx.x] = s;
    __syncthreads();
    for (int off = 128; off > 0; off >>= 1) {
        if (threadIdx.x < off) sh[threadIdx.x] += sh[threadIdx.x + off];
        __syncthreads();
    }
    if (threadIdx.x == 0) scales[b] = logf((float)sh[0]) / LN512;
}

// ---------------------------------------------------------------- tiled GEMM mainloop
// 2-slot / 32KB, ONE barrier per iteration, bank-swizzled LDS.
// C(128x128) += A(128xK) * BT(128xK)^T. 256 thr = 4 waves 2x2; wave does 64x64.
// Slots: A at smem+slot*4096, B at smem+8192+slot*4096 (elements). 32KB total
// -> 5 blocks/CU co-residency (the R12 48KB layout capped at 3).
// Per iter k: wait vmcnt(0) [own tile-k, issued 1 iter earlier; L2-hit ~200cyc
// << 1 iter lead] -> barrier -> issue DMA tile k+1 into slot (k+1)%2 [== slot
// consumed at k-1; its readers lgkm-pinned before the previous barrier] ->
// ds_read slot k%2 + MFMA -> lgkm-pin.
struct TileCtx {
    int tid, wave, lane, quad, l16, wm, wn, c0, c1, sw;
};
static __device__ __forceinline__ TileCtx make_ctx() {
    TileCtx t;
    t.tid = threadIdx.x;
    t.wave = t.tid >> 6; t.lane = t.tid & 63;
    t.quad = t.lane >> 4; t.l16 = t.lane & 15;
    t.wm = (t.wave & 1) * 64;
    t.wn = (t.wave >> 1) * 64;
    t.c0 = t.tid;
    t.c1 = t.tid + 256;
    t.sw = (t.l16 >> 1) & 3;     // bank swizzle key (row>>1)&3
    return t;
}

static __device__ __forceinline__ void gemm_mainloop_2s(
    const TileCtx& t,
    const _Float16* __restrict__ Ag, int lda,   // &A[m0][0]
    const _Float16* __restrict__ Bg, int ldb,   // &BT[n0][0]
    int K, _Float16* smem, floatx4 acc[4][4])
{
    const int ar0 = t.c0 >> 2, ak0 = ((t.c0 & 3) ^ ((t.c0 >> 3) & 3)) * 8;
    const int ar1 = t.c1 >> 2, ak1 = ((t.c1 & 3) ^ ((t.c1 >> 3) & 3)) * 8;
    const _Float16* a0 = Ag + (size_t)ar0 * lda + ak0;
    const _Float16* a1 = Ag + (size_t)ar1 * lda + ak1;
    const _Float16* b0 = Bg + (size_t)ar0 * ldb + ak0;
    const _Float16* b1 = Bg + (size_t)ar1 * ldb + ak1;
    _Float16* Asl = smem + t.c0 * 8;           // my A staging slot base (slot 0)
    _Float16* Bsl = smem + 8192 + t.c0 * 8;    // my B staging slot base (slot 0)
    const int nIter = K >> 5;

    // fragment read offsets (element units): row*32 + (quad ^ sw)*8
    const int qsw = (t.quad ^ t.sw) * 8;

    // prologue: tile 0 -> slot 0
    load16(a0, Asl);        load16(a1, Asl + 2048);
    load16(b0, Bsl);        load16(b1, Bsl + 2048);

    int sc = 0;   // consume slot (k%2)
    for (int k = 0; k < nIter; ++k) {
        WAIT_VM(0);        // own tile-k loads landed (issued 1 iter ago)
        BARRIER_RAW();     // all waves: tile-k landed, other slot's readers done
        if (k + 1 < nIter) {
            const int off = (sc ^ 1) * 4096;
            const int k0 = (k + 1) << 5;
            load16(a0 + k0, Asl + off); load16(a1 + k0, Asl + off + 2048);
            load16(b0 + k0, Bsl + off); load16(b1 + k0, Bsl + off + 2048);
        }
        const _Float16* Ab = smem + sc * 4096;
        const _Float16* Bb = smem + 8192 + sc * 4096;
        half8 af[4], bf[4];
#pragma unroll
        for (int mt = 0; mt < 4; ++mt)
            af[mt] = *reinterpret_cast<const half8*>(Ab + (t.wm + mt * 16 + t.l16) * 32 + qsw);
#pragma unroll
        for (int nt = 0; nt < 4; ++nt)
            bf[nt] = *reinterpret_cast<const half8*>(Bb + (t.wn + nt * 16 + t.l16) * 32 + qsw);
#pragma unroll
        for (int mt = 0; mt < 4; ++mt)
#pragma unroll
            for (int nt = 0; nt < 4; ++nt)
                acc[mt][nt] = __builtin_amdgcn_mfma_f32_16x16x32_f16(af[mt], bf[nt], acc[mt][nt], 0, 0, 0);
        WAIT_LGKM0();      // pin my ds_reads before the next barrier (slot-overwrite guard)
        sc ^= 1;
    }
}

// ---------------------------------------------------------------- GEMM1: silu(H@Wi) -> u, vT, q, k
// 1D grid 1600, XCD-banded: xcd=f%8 owns m-band [8*xcd,8*xcd+8); n slow within band.
__global__ __launch_bounds__(256) void gemm1_kernel(
    const _Float16* __restrict__ Hb, const _Float16* __restrict__ WiT,
    const float* __restrict__ qg, const float* __restrict__ kg,
    _Float16* __restrict__ u, _Float16* __restrict__ vT,
    _Float16* __restrict__ q, _Float16* __restrict__ k)
{
    __shared__ _Float16 smem[16384];
    TileCtx t = make_ctx();
    const int f = blockIdx.x;
    const int xcd = f & 7, i = f >> 3;          // i: 0..199
    const int m0 = ((xcd << 3) | (i & 7)) * 128;
    const int n0 = (i >> 3) * 128;              // 0..24

    floatx4 acc[4][4] = {};
    gemm_mainloop_2s(t, Hb + (size_t)m0 * HID, HID, WiT + (size_t)n0 * HID, HID, HID, smem, acc);

    if (n0 >= INTER && n0 < 2 * INTER) {
        __syncthreads();   // mainloop has no trailing barrier; smem is reused below
        // vT path: transpose via LDS (XOR swizzle), then coalesced 16B stores.
        const int bb = m0 >> 11, sloc = m0 & (SEQ - 1), cI = n0 - INTER;
#pragma unroll
        for (int mt = 0; mt < 4; ++mt) {
#pragma unroll
            for (int nt = 0; nt < 4; ++nt) {
                int c = t.wn + nt * 16 + t.l16;
#pragma unroll
                for (int i2 = 0; i2 < 4; ++i2) {
                    int r = t.wm + mt * 16 + t.quad * 4 + i2;
                    float x = acc[mt][nt][i2];
                    float y = x / (1.0f + __expf(-x));   // silu
                    smem[c * 128 + (r ^ ((c & 15) << 3))] = (_Float16)y;
                }
            }
        }
        __syncthreads();
#pragma unroll
        for (int p = 0; p < 8; ++p) {
            int chunk = t.tid + p * 256;         // 2048 chunks of 8 halves
            int cl = chunk >> 4, sc = chunk & 15;
            int scs = sc ^ (cl & 15);
            half8 v = *reinterpret_cast<const half8*>(smem + cl * 128 + scs * 8);
            *reinterpret_cast<half8*>(vT + ((size_t)bb * INTER + cI + cl) * SEQ + sloc + sc * 8) = v;
        }
    } else {
#pragma unroll
        for (int mt = 0; mt < 4; ++mt) {
#pragma unroll
            for (int nt = 0; nt < 4; ++nt) {
                int col = n0 + t.wn + nt * 16 + t.l16;
#pragma unroll
                for (int i2 = 0; i2 < 4; ++i2) {
                    int row = m0 + t.wm + mt * 16 + t.quad * 4 + i2;
                    float x = acc[mt][nt][i2];
                    float y = x / (1.0f + __expf(-x));   // silu
                    if (n0 < INTER) {
                        u[(size_t)row * INTER + col] = (_Float16)y;
                    } else {
                        int c = col - 2 * INTER;
                        q[(size_t)row * DK + c] = (_Float16)(y * qg[c]);
                        k[(size_t)row * DK + c] = (_Float16)(y * kg[c]);
                    }
                }
            }
        }
    }
}

// ---------------------------------------------------------------- scores + softmax -> P (f16)
__global__ __launch_bounds__(256) void scores_kernel(
    const _Float16* __restrict__ q, const _Float16* __restrict__ k,
    const int* __restrict__ mask, const float* __restrict__ scales,
    _Float16* __restrict__ P)
{
    const int b = blockIdx.y;
    const int m0 = blockIdx.x * 16;
    const int tid = threadIdx.x;
    const int wave = tid >> 6, lane = tid & 63, quad = lane >> 4, l16 = lane & 15;
    const float scale = scales[b];

    half8 aq[4];
    const _Float16* qrow = q + (b * SEQ + m0 + l16) * DK + quad * 8;
#pragma unroll
    for (int kk = 0; kk < 4; ++kk) aq[kk] = *reinterpret_cast<const half8*>(qrow + kk * 32);

    floatx4 sc[32];
#pragma unroll
    for (int nt = 0; nt < 32; ++nt) {
        int n0 = nt * 64 + wave * 16;
        const _Float16* krow = k + (b * SEQ + n0 + l16) * DK + quad * 8;
        floatx4 acc = {};
#pragma unroll
        for (int kk = 0; kk < 4; ++kk) {
            half8 bq = *reinterpret_cast<const half8*>(krow + kk * 32);
            acc = __builtin_amdgcn_mfma_f32_16x16x32_f16(aq[kk], bq, acc, 0, 0, 0);
        }
        sc[nt] = acc;
    }

    const float rs = 0.08838834764831845f * scale;
    const float mval = -1e12f * scale;
    float rmax[4] = {-3.4e38f, -3.4e38f, -3.4e38f, -3.4e38f};
#pragma unroll
    for (int nt = 0; nt < 32; ++nt) {
        int ncol = nt * 64 + wave * 16 + l16;
        bool mok = mask[b * SEQ + ncol] != 0;
#pragma unroll
        for (int i = 0; i < 4; ++i) {
            float s = mok ? sc[nt][i] * rs : mval;
            sc[nt][i] = s;
            rmax[i] = fmaxf(rmax[i], s);
        }
    }
#pragma unroll
    for (int i = 0; i < 4; ++i) {
#pragma unroll
        for (int off = 1; off < 16; off <<= 1)
            rmax[i] = fmaxf(rmax[i], __shfl_xor(rmax[i], off, 64));
    }
    __shared__ float redmax[4][16];
    __shared__ float redsum[4][16];
    if (l16 == 0) {
#pragma unroll
        for (int i = 0; i < 4; ++i) redmax[wave][quad * 4 + i] = rmax[i];
    }
    __syncthreads();
#pragma unroll
    for (int i = 0; i < 4; ++i) {
        int r = quad * 4 + i;
        rmax[i] = fmaxf(fmaxf(redmax[0][r], redmax[1][r]), fmaxf(redmax[2][r], redmax[3][r]));
    }
    float rsum[4] = {0.f, 0.f, 0.f, 0.f};
#pragma unroll
    for (int nt = 0; nt < 32; ++nt) {
#pragma unroll
        for (int i = 0; i < 4; ++i) {
            float e = __expf(sc[nt][i] - rmax[i]);
            sc[nt][i] = e;
            rsum[i] += e;
        }
    }
#pragma unroll
    for (int i = 0; i < 4; ++i) {
#pragma unroll
        for (int off = 1; off < 16; off <<= 1) rsum[i] += __shfl_xor(rsum[i], off, 64);
    }
    if (l16 == 0) {
#pragma unroll
        for (int i = 0; i < 4; ++i) redsum[wave][quad * 4 + i] = rsum[i];
    }
    __syncthreads();
#pragma unroll
    for (int i = 0; i < 4; ++i) {
        int r = quad * 4 + i;
        float tot = redsum[0][r] + redsum[1][r] + redsum[2][r] + redsum[3][r];
        float inv = 1.0f / tot;
        int row = m0 + r;
        _Float16* Prow = P + ((size_t)b * SEQ + row) * SEQ;
#pragma unroll
        for (int nt = 0; nt < 32; ++nt) {
            int ncol = nt * 64 + wave * 16 + l16;
            Prow[ncol] = (_Float16)(sc[nt][i] * inv);
        }
    }
}

// ---------------------------------------------------------------- PV: u <- u .* (P @ v)   (in place)
// 1D grid 768: xcd=f%8, i=f/8 (0..95); batch=i/24; j=i%24; m=xcd*2+(j&1); n=j/2.
__global__ __launch_bounds__(256) void pv_kernel(
    const _Float16* __restrict__ P, const _Float16* __restrict__ vT,
    _Float16* __restrict__ u)
{
    __shared__ _Float16 smem[16384];
    TileCtx t = make_ctx();
    const int f = blockIdx.x;
    const int xcd = f & 7, i = f >> 3;          // i: 0..95
    const int b = i / 24, j = i % 24;
    const int m0 = (xcd * 2 + (j & 1)) * 128;
    const int n0 = (j >> 1) * 128;
    const _Float16* Pb  = P  + (size_t)b * SEQ * SEQ;
    const _Float16* vTb = vT + (size_t)b * INTER * SEQ;

    floatx4 acc[4][4] = {};
    gemm_mainloop_2s(t, Pb + (size_t)m0 * SEQ, SEQ, vTb + (size_t)n0 * SEQ, SEQ, SEQ, smem, acc);

#pragma unroll
    for (int mt = 0; mt < 4; ++mt) {
#pragma unroll
        for (int nt = 0; nt < 4; ++nt) {
            int col = n0 + t.wn + nt * 16 + t.l16;
#pragma unroll
            for (int i2 = 0; i2 < 4; ++i2) {
                int row = m0 + t.wm + mt * 16 + t.quad * 4 + i2;
                size_t gidx = ((size_t)(b * SEQ + row)) * INTER + col;
                float uv = (float)u[gidx];
                u[gidx] = (_Float16)(acc[mt][nt][i2] * uv);
            }
        }
    }
}

// ---------------------------------------------------------------- GEMM2: out = t @ Wo (fp32 out)
// 1D grid 384: xcd=f%8, i=f/8 (0..47); m=xcd*8+(i&7); n=i>>3 (0..5).
__global__ __launch_bounds__(256) void gemm2_kernel(
    const _Float16* __restrict__ tin, const _Float16* __restrict__ WoT,
    float* __restrict__ out)
{
    __shared__ _Float16 smem[16384];
    TileCtx t = make_ctx();
    const int f = blockIdx.x;
    const int xcd = f & 7, i = f >> 3;          // i: 0..47
    const int m0 = ((xcd << 3) | (i & 7)) * 128;
    const int n0 = (i >> 3) * 128;              // 0..5

    floatx4 acc[4][4] = {};
    gemm_mainloop_2s(t, tin + (size_t)m0 * INTER, INTER, WoT + (size_t)n0 * INTER, INTER, INTER, smem, acc);

#pragma unroll
    for (int mt = 0; mt < 4; ++mt) {
#pragma unroll
        for (int nt = 0; nt < 4; ++nt) {
            int col = n0 + t.wn + nt * 16 + t.l16;
#pragma unroll
            for (int i2 = 0; i2 < 4; ++i2) {
                int row = m0 + t.wm + mt * 16 + t.quad * 4 + i2;
                out[(size_t)row * HID + col] = acc[mt][nt][i2];
            }
        }
    }
}

// ---------------------------------------------------------------- launch
extern "C" void kernel_launch(void* const* d_in, const int* in_sizes, int n_in,
                              void* d_out, int out_size, void* d_ws, size_t ws_size,
                              hipStream_t stream) {
    const float* H    = (const float*)d_in[0];
    const float* Wi   = (const float*)d_in[1];
    const float* Wo   = (const float*)d_in[2];
    const float* qg   = (const float*)d_in[3];
    const float* kg   = (const float*)d_in[4];
    const int*   mask = (const int*)d_in[5];
    float* out = (float*)d_out;

    char* base = (char*)d_ws;
    size_t off = 0;
    auto alloc = [&](size_t bytes) { void* p = base + off; off = (off + bytes + 255) & ~(size_t)255; return p; };
    _Float16* Hb   = (_Float16*)alloc((size_t)MROWS * HID * 2);
    _Float16* WiT  = (_Float16*)alloc((size_t)NTOT * HID * 2);
    _Float16* WoT  = (_Float16*)alloc((size_t)HID * INTER * 2);
    _Float16* u    = (_Float16*)alloc((size_t)MROWS * INTER * 2);   // becomes t in-place after pv
    _Float16* vT   = (_Float16*)alloc((size_t)BATCH * INTER * SEQ * 2);
    _Float16* q    = (_Float16*)alloc((size_t)MROWS * DK * 2);
    _Float16* k    = (_Float16*)alloc((size_t)MROWS * DK * 2);
    _Float16* P    = (_Float16*)alloc((size_t)BATCH * SEQ * SEQ * 2);
    float*    scales = (float*)alloc(4 * sizeof(float));

    {
        int n = MROWS * HID;
        cast_h_kernel<<<n / 8 / 256, 256, 0, stream>>>(H, Hb, n);
        trans_wi_kernel<<<dim3(NTOT / 32, HID / 32), dim3(32, 8), 0, stream>>>(Wi, WiT);
        trans_wo_kernel<<<dim3(HID / 32, INTER / 32), dim3(32, 8), 0, stream>>>(Wo, WoT);
        mask_scales_kernel<<<BATCH, 256, 0, stream>>>(mask, scales);
    }
    // GEMM1: M=8192 N=3200 K=768
    gemm1_kernel<<<1600, 256, 0, stream>>>(Hb, WiT, qg, kg, u, vT, q, k);
    // scores + softmax -> P
    {
        dim3 grid(SEQ / 16, BATCH);
        scores_kernel<<<grid, 256, 0, stream>>>(q, k, mask, scales, P);
    }
    // PV: per batch M=2048 N=1536 K=2048
    pv_kernel<<<768, 256, 0, stream>>>(P, vT, u);
    // GEMM2: M=8192 N=768 K=1536
    gemm2_kernel<<<384, 256, 0, stream>>>(u, WoT, out);
}

// Round 14
// 307.655 us; speedup vs baseline: 1.1013x; 1.1013x over previous
//
#include <hip/hip_runtime.h>
#include <hip/hip_bf16.h>
#include <math.h>

// Problem constants
#define BATCH 4
#define SEQ   2048
#define HID   768
#define INTER 1536
#define DK    128
#define NTOT  3200      // 2*INTER + DK
#define MROWS 8192      // BATCH*SEQ
#define LN512 6.2383246250395075f

typedef _Float16 half8   __attribute__((ext_vector_type(8)));
typedef float    floatx4 __attribute__((ext_vector_type(4)));
typedef float    floatx16 __attribute__((ext_vector_type(16)));

typedef const __attribute__((address_space(1))) unsigned int* gas1_t;
typedef __attribute__((address_space(3))) unsigned int* las3_t;

static __device__ __forceinline__ void load16(const _Float16* g, _Float16* l) {
    __builtin_amdgcn_global_load_lds((gas1_t)g, (las3_t)l, 16, 0, 0);
}
#define WAIT_VM(N)    asm volatile("s_waitcnt vmcnt(" #N ")" ::: "memory")
#define WAIT_LGKM0()  asm volatile("s_waitcnt lgkmcnt(0)" ::: "memory")
#define BARRIER_RAW() asm volatile("s_barrier" ::: "memory")

// ---------------------------------------------------------------- prep kernels
__global__ void cast_h_kernel(const float* __restrict__ in, _Float16* __restrict__ out, int n) {
    int i = (blockIdx.x * blockDim.x + threadIdx.x) * 8;
    if (i < n) {
        float4 a = *reinterpret_cast<const float4*>(in + i);
        float4 b = *reinterpret_cast<const float4*>(in + i + 4);
        half8 h = {(_Float16)a.x, (_Float16)a.y, (_Float16)a.z, (_Float16)a.w,
                   (_Float16)b.x, (_Float16)b.y, (_Float16)b.z, (_Float16)b.w};
        *reinterpret_cast<half8*>(out + i) = h;
    }
}

__global__ void trans_wi_kernel(const float* __restrict__ Wi, _Float16* __restrict__ WiT) {
    __shared__ _Float16 tile[32][33];
    const int c0 = blockIdx.x * 32, r0 = blockIdx.y * 32;
    const int tx = threadIdx.x, ty = threadIdx.y;
#pragma unroll
    for (int j = 0; j < 32; j += 8)
        tile[tx][ty + j] = (_Float16)Wi[(size_t)(r0 + ty + j) * NTOT + c0 + tx];
    __syncthreads();
#pragma unroll
    for (int j = 0; j < 32; j += 8)
        WiT[(size_t)(c0 + ty + j) * HID + r0 + tx] = tile[ty + j][tx];
}

__global__ void trans_wo_kernel(const float* __restrict__ Wo, _Float16* __restrict__ WoT) {
    __shared__ _Float16 tile[32][33];
    const int c0 = blockIdx.x * 32, r0 = blockIdx.y * 32;
    const int tx = threadIdx.x, ty = threadIdx.y;
#pragma unroll
    for (int j = 0; j < 32; j += 8)
        tile[tx][ty + j] = (_Float16)Wo[(size_t)(r0 + ty + j) * HID + c0 + tx];
    __syncthreads();
#pragma unroll
    for (int j = 0; j < 32; j += 8)
        WoT[(size_t)(c0 + ty + j) * INTER + r0 + tx] = tile[ty + j][tx];
}

__global__ void mask_scales_kernel(const int* __restrict__ mask, float* __restrict__ scales) {
    __shared__ int sh[256];
    int b = blockIdx.x;
    int s = 0;
    for (int i = threadIdx.x; i < SEQ; i += 256) s += mask[b * SEQ + i];
    sh[threadIdx.x] = s;
    __syncthreads();
    for (int off = 128; off > 0; off >>= 1) {
        if (threadIdx.x < off) sh[threadIdx.x] += sh[threadIdx.x + off];
        __syncthreads();
    }
    if (threadIdx.x == 0) scales[b] = logf((float)sh[0]) / LN512;
}

// ---------------------------------------------------------------- shared tile ctx
struct TileCtx {
    int tid, wave, lane, quad, l16, l31, half, wm, wn, c0, c1;
};
static __device__ __forceinline__ TileCtx make_ctx() {
    TileCtx t;
    t.tid = threadIdx.x;
    t.wave = t.tid >> 6; t.lane = t.tid & 63;
    t.quad = t.lane >> 4; t.l16 = t.lane & 15;
    t.l31 = t.lane & 31;  t.half = t.lane >> 5;
    t.wm = (t.wave & 1) * 64;
    t.wn = (t.wave >> 1) * 64;
    t.c0 = t.tid;
    t.c1 = t.tid + 256;
    return t;
}

// ================================================================ mainloop A: 16x16x32 (R12-proven, gemm1)
// 3-slot / 48KB, 1 barrier/iter, swizzle s16(r) = (r>>1)&3.
static __device__ __forceinline__ void gemm_mainloop_3s16(
    const TileCtx& t,
    const _Float16* __restrict__ Ag, int lda,
    const _Float16* __restrict__ Bg, int ldb,
    int K, _Float16* smem, floatx4 acc[4][4])
{
    const int ar0 = t.c0 >> 2, ak0 = ((t.c0 & 3) ^ ((t.c0 >> 3) & 3)) * 8;
    const int ar1 = t.c1 >> 2, ak1 = ((t.c1 & 3) ^ ((t.c1 >> 3) & 3)) * 8;
    const _Float16* a0 = Ag + (size_t)ar0 * lda + ak0;
    const _Float16* a1 = Ag + (size_t)ar1 * lda + ak1;
    const _Float16* b0 = Bg + (size_t)ar0 * ldb + ak0;
    const _Float16* b1 = Bg + (size_t)ar1 * ldb + ak1;
    _Float16* Asl = smem + t.c0 * 8;
    _Float16* Bsl = smem + 12288 + t.c0 * 8;
    const int nIter = K >> 5;
    const int sw = (t.l16 >> 1) & 3;
    const int qsw = (t.quad ^ sw) * 8;

    load16(a0, Asl);        load16(a1, Asl + 2048);
    load16(b0, Bsl);        load16(b1, Bsl + 2048);
    if (nIter > 1) {
        load16(a0 + 32, Asl + 4096); load16(a1 + 32, Asl + 6144);
        load16(b0 + 32, Bsl + 4096); load16(b1 + 32, Bsl + 6144);
    }

    int sc = 0, sp = 2;
    for (int k = 0; k < nIter; ++k) {
        if (k + 1 < nIter) { WAIT_VM(4); } else { WAIT_VM(0); }
        BARRIER_RAW();
        if (k + 2 < nIter) {
            const int off = sp * 4096;
            const int k0 = (k + 2) << 5;
            load16(a0 + k0, Asl + off); load16(a1 + k0, Asl + off + 2048);
            load16(b0 + k0, Bsl + off); load16(b1 + k0, Bsl + off + 2048);
        }
        const _Float16* Ab = smem + sc * 4096;
        const _Float16* Bb = smem + 12288 + sc * 4096;
        half8 af[4], bf[4];
#pragma unroll
        for (int mt = 0; mt < 4; ++mt)
            af[mt] = *reinterpret_cast<const half8*>(Ab + (t.wm + mt * 16 + t.l16) * 32 + qsw);
#pragma unroll
        for (int nt = 0; nt < 4; ++nt)
            bf[nt] = *reinterpret_cast<const half8*>(Bb + (t.wn + nt * 16 + t.l16) * 32 + qsw);
#pragma unroll
        for (int mt = 0; mt < 4; ++mt)
#pragma unroll
            for (int nt = 0; nt < 4; ++nt)
                acc[mt][nt] = __builtin_amdgcn_mfma_f32_16x16x32_f16(af[mt], bf[nt], acc[mt][nt], 0, 0, 0);
        WAIT_LGKM0();
        sc = (sc == 2) ? 0 : sc + 1;
        sp = (sp == 2) ? 0 : sp + 1;
    }
}

// ================================================================ mainloop B: 32x32x16 (pv/gemm2)
// Same 3-slot/48KB/1-barrier skeleton; swizzle s32(r) = ((r>>1)^(r>>3))&3 so the
// 32-row fragment reads hit all 32 bank groups (old s16 aliased r,r+8,r+16,r+24).
// Per iter: 8 MFMA 32x32x16 (2 mt x 2 nt x 2 ksteps), 8 ds_read_b128 (same bytes).
static __device__ __forceinline__ void gemm_mainloop_3s32(
    const TileCtx& t,
    const _Float16* __restrict__ Ag, int lda,
    const _Float16* __restrict__ Bg, int ldb,
    int K, _Float16* smem, floatx16 acc[2][2])
{
    const int r0i = t.c0 >> 2, s0 = (((r0i >> 1) ^ (r0i >> 3)) & 3);
    const int r1i = t.c1 >> 2, s1 = (((r1i >> 1) ^ (r1i >> 3)) & 3);
    const int ak0 = ((t.c0 & 3) ^ s0) * 8;
    const int ak1 = ((t.c1 & 3) ^ s1) * 8;
    const _Float16* a0 = Ag + (size_t)r0i * lda + ak0;
    const _Float16* a1 = Ag + (size_t)r1i * lda + ak1;
    const _Float16* b0 = Bg + (size_t)r0i * ldb + ak0;
    const _Float16* b1 = Bg + (size_t)r1i * ldb + ak1;
    _Float16* Asl = smem + t.c0 * 8;
    _Float16* Bsl = smem + 12288 + t.c0 * 8;
    const int nIter = K >> 5;

    // fragment-read chunk swizzle depends only on (l31): rows read are off + l31,
    // off multiple of 32 -> s32(row) = ((l31>>1)^(l31>>3))&3
    const int fsw = ((t.l31 >> 1) ^ (t.l31 >> 3)) & 3;

    load16(a0, Asl);        load16(a1, Asl + 2048);
    load16(b0, Bsl);        load16(b1, Bsl + 2048);
    if (nIter > 1) {
        load16(a0 + 32, Asl + 4096); load16(a1 + 32, Asl + 6144);
        load16(b0 + 32, Bsl + 4096); load16(b1 + 32, Bsl + 6144);
    }

    int sc = 0, sp = 2;
    for (int k = 0; k < nIter; ++k) {
        if (k + 1 < nIter) { WAIT_VM(4); } else { WAIT_VM(0); }
        BARRIER_RAW();
        if (k + 2 < nIter) {
            const int off = sp * 4096;
            const int k0 = (k + 2) << 5;
            load16(a0 + k0, Asl + off); load16(a1 + k0, Asl + off + 2048);
            load16(b0 + k0, Bsl + off); load16(b1 + k0, Bsl + off + 2048);
        }
        const _Float16* Ab = smem + sc * 4096;
        const _Float16* Bb = smem + 12288 + sc * 4096;
        half8 af[2][2], bf[2][2];   // [tile][kstep]
#pragma unroll
        for (int mt = 0; mt < 2; ++mt)
#pragma unroll
            for (int h = 0; h < 2; ++h)
                af[mt][h] = *reinterpret_cast<const half8*>(
                    Ab + (t.wm + mt * 32 + t.l31) * 32 + (((h * 2 + t.half) ^ fsw) * 8));
#pragma unroll
        for (int nt = 0; nt < 2; ++nt)
#pragma unroll
            for (int h = 0; h < 2; ++h)
                bf[nt][h] = *reinterpret_cast<const half8*>(
                    Bb + (t.wn + nt * 32 + t.l31) * 32 + (((h * 2 + t.half) ^ fsw) * 8));
#pragma unroll
        for (int h = 0; h < 2; ++h)
#pragma unroll
            for (int mt = 0; mt < 2; ++mt)
#pragma unroll
                for (int nt = 0; nt < 2; ++nt)
                    acc[mt][nt] = __builtin_amdgcn_mfma_f32_32x32x16_f16(af[mt][h], bf[nt][h], acc[mt][nt], 0, 0, 0);
        WAIT_LGKM0();
        sc = (sc == 2) ? 0 : sc + 1;
        sp = (sp == 2) ? 0 : sp + 1;
    }
}

// ---------------------------------------------------------------- GEMM1: silu(H@Wi) -> u, vT, q, k
// 1D grid 1600, XCD-banded. R12-proven 16x16 mainloop.
__global__ __launch_bounds__(256) void gemm1_kernel(
    const _Float16* __restrict__ Hb, const _Float16* __restrict__ WiT,
    const float* __restrict__ qg, const float* __restrict__ kg,
    _Float16* __restrict__ u, _Float16* __restrict__ vT,
    _Float16* __restrict__ q, _Float16* __restrict__ k)
{
    __shared__ _Float16 smem[24576];
    TileCtx t = make_ctx();
    const int f = blockIdx.x;
    const int xcd = f & 7, i = f >> 3;
    const int m0 = ((xcd << 3) | (i & 7)) * 128;
    const int n0 = (i >> 3) * 128;

    floatx4 acc[4][4] = {};
    gemm_mainloop_3s16(t, Hb + (size_t)m0 * HID, HID, WiT + (size_t)n0 * HID, HID, HID, smem, acc);

    if (n0 >= INTER && n0 < 2 * INTER) {
        __syncthreads();
        const int bb = m0 >> 11, sloc = m0 & (SEQ - 1), cI = n0 - INTER;
#pragma unroll
        for (int mt = 0; mt < 4; ++mt) {
#pragma unroll
            for (int nt = 0; nt < 4; ++nt) {
                int c = t.wn + nt * 16 + t.l16;
#pragma unroll
                for (int i2 = 0; i2 < 4; ++i2) {
                    int r = t.wm + mt * 16 + t.quad * 4 + i2;
                    float x = acc[mt][nt][i2];
                    float y = x / (1.0f + __expf(-x));
                    smem[c * 128 + (r ^ ((c & 15) << 3))] = (_Float16)y;
                }
            }
        }
        __syncthreads();
#pragma unroll
        for (int p = 0; p < 8; ++p) {
            int chunk = t.tid + p * 256;
            int cl = chunk >> 4, sc = chunk & 15;
            int scs = sc ^ (cl & 15);
            half8 v = *reinterpret_cast<const half8*>(smem + cl * 128 + scs * 8);
            *reinterpret_cast<half8*>(vT + ((size_t)bb * INTER + cI + cl) * SEQ + sloc + sc * 8) = v;
        }
    } else {
#pragma unroll
        for (int mt = 0; mt < 4; ++mt) {
#pragma unroll
            for (int nt = 0; nt < 4; ++nt) {
                int col = n0 + t.wn + nt * 16 + t.l16;
#pragma unroll
                for (int i2 = 0; i2 < 4; ++i2) {
                    int row = m0 + t.wm + mt * 16 + t.quad * 4 + i2;
                    float x = acc[mt][nt][i2];
                    float y = x / (1.0f + __expf(-x));
                    if (n0 < INTER) {
                        u[(size_t)row * INTER + col] = (_Float16)y;
                    } else {
                        int c = col - 2 * INTER;
                        q[(size_t)row * DK + c] = (_Float16)(y * qg[c]);
                        k[(size_t)row * DK + c] = (_Float16)(y * kg[c]);
                    }
                }
            }
        }
    }
}

// ---------------------------------------------------------------- scores + softmax -> P (f16)
// 1D grid 512, XCD-batched: xcd=f&7 handles batch xcd>>1 only (k_b L2-resident).
__global__ __launch_bounds__(256) void scores_kernel(
    const _Float16* __restrict__ q, const _Float16* __restrict__ k,
    const int* __restrict__ mask, const float* __restrict__ scales,
    _Float16* __restrict__ P)
{
    const int f = blockIdx.x;
    const int xcd = f & 7, i = f >> 3;          // i: 0..63
    const int b = xcd >> 1;
    const int m0 = ((xcd & 1) * 64 + i) * 16;
    const int tid = threadIdx.x;
    const int wave = tid >> 6, lane = tid & 63, quad = lane >> 4, l16 = lane & 15;
    const float scale = scales[b];

    half8 aq[4];
    const _Float16* qrow = q + (b * SEQ + m0 + l16) * DK + quad * 8;
#pragma unroll
    for (int kk = 0; kk < 4; ++kk) aq[kk] = *reinterpret_cast<const half8*>(qrow + kk * 32);

    floatx4 sc[32];
#pragma unroll
    for (int nt = 0; nt < 32; ++nt) {
        int n0 = nt * 64 + wave * 16;
        const _Float16* krow = k + (b * SEQ + n0 + l16) * DK + quad * 8;
        floatx4 acc = {};
#pragma unroll
        for (int kk = 0; kk < 4; ++kk) {
            half8 bq = *reinterpret_cast<const half8*>(krow + kk * 32);
            acc = __builtin_amdgcn_mfma_f32_16x16x32_f16(aq[kk], bq, acc, 0, 0, 0);
        }
        sc[nt] = acc;
    }

    const float rs = 0.08838834764831845f * scale;
    const float mval = -1e12f * scale;
    float rmax[4] = {-3.4e38f, -3.4e38f, -3.4e38f, -3.4e38f};
#pragma unroll
    for (int nt = 0; nt < 32; ++nt) {
        int ncol = nt * 64 + wave * 16 + l16;
        bool mok = mask[b * SEQ + ncol] != 0;
#pragma unroll
        for (int i2 = 0; i2 < 4; ++i2) {
            float s = mok ? sc[nt][i2] * rs : mval;
            sc[nt][i2] = s;
            rmax[i2] = fmaxf(rmax[i2], s);
        }
    }
#pragma unroll
    for (int i2 = 0; i2 < 4; ++i2) {
#pragma unroll
        for (int off = 1; off < 16; off <<= 1)
            rmax[i2] = fmaxf(rmax[i2], __shfl_xor(rmax[i2], off, 64));
    }
    __shared__ float redmax[4][16];
    __shared__ float redsum[4][16];
    if (l16 == 0) {
#pragma unroll
        for (int i2 = 0; i2 < 4; ++i2) redmax[wave][quad * 4 + i2] = rmax[i2];
    }
    __syncthreads();
#pragma unroll
    for (int i2 = 0; i2 < 4; ++i2) {
        int r = quad * 4 + i2;
        rmax[i2] = fmaxf(fmaxf(redmax[0][r], redmax[1][r]), fmaxf(redmax[2][r], redmax[3][r]));
    }
    float rsum[4] = {0.f, 0.f, 0.f, 0.f};
#pragma unroll
    for (int nt = 0; nt < 32; ++nt) {
#pragma unroll
        for (int i2 = 0; i2 < 4; ++i2) {
            float e = __expf(sc[nt][i2] - rmax[i2]);
            sc[nt][i2] = e;
            rsum[i2] += e;
        }
    }
#pragma unroll
    for (int i2 = 0; i2 < 4; ++i2) {
#pragma unroll
        for (int off = 1; off < 16; off <<= 1) rsum[i2] += __shfl_xor(rsum[i2], off, 64);
    }
    if (l16 == 0) {
#pragma unroll
        for (int i2 = 0; i2 < 4; ++i2) redsum[wave][quad * 4 + i2] = rsum[i2];
    }
    __syncthreads();
#pragma unroll
    for (int i2 = 0; i2 < 4; ++i2) {
        int r = quad * 4 + i2;
        float tot = redsum[0][r] + redsum[1][r] + redsum[2][r] + redsum[3][r];
        float inv = 1.0f / tot;
        int row = m0 + r;
        _Float16* Prow = P + ((size_t)b * SEQ + row) * SEQ;
#pragma unroll
        for (int nt = 0; nt < 32; ++nt) {
            int ncol = nt * 64 + wave * 16 + l16;
            Prow[ncol] = (_Float16)(sc[nt][i2] * inv);
        }
    }
}

// ---------------------------------------------------------------- PV: u <- u .* (P @ v)  (32x32 MFMA)
// 1D grid 768: xcd=f%8, i=f/8 (0..95); batch=i/24; j=i%24; m=xcd*2+(j&1); n=j/2.
__global__ __launch_bounds__(256) void pv_kernel(
    const _Float16* __restrict__ P, const _Float16* __restrict__ vT,
    _Float16* __restrict__ u)
{
    __shared__ _Float16 smem[24576];
    TileCtx t = make_ctx();
    const int f = blockIdx.x;
    const int xcd = f & 7, i = f >> 3;
    const int b = i / 24, j = i % 24;
    const int m0 = (xcd * 2 + (j & 1)) * 128;
    const int n0 = (j >> 1) * 128;
    const _Float16* Pb  = P  + (size_t)b * SEQ * SEQ;
    const _Float16* vTb = vT + (size_t)b * INTER * SEQ;

    floatx16 acc[2][2] = {};
    gemm_mainloop_3s32(t, Pb + (size_t)m0 * SEQ, SEQ, vTb + (size_t)n0 * SEQ, SEQ, SEQ, smem, acc);

    // C/D 32x32: col = lane&31, row = (reg&3) + 8*(reg>>2) + 4*(lane>>5)
#pragma unroll
    for (int mt = 0; mt < 2; ++mt) {
#pragma unroll
        for (int nt = 0; nt < 2; ++nt) {
            int col = n0 + t.wn + nt * 32 + t.l31;
#pragma unroll
            for (int reg = 0; reg < 16; ++reg) {
                int row = m0 + t.wm + mt * 32 + (reg & 3) + 8 * (reg >> 2) + 4 * t.half;
                size_t gidx = ((size_t)(b * SEQ + row)) * INTER + col;
                float uv = (float)u[gidx];
                u[gidx] = (_Float16)(acc[mt][nt][reg] * uv);
            }
        }
    }
}

// ---------------------------------------------------------------- GEMM2: out = t @ Wo (fp32 out, 32x32 MFMA)
// 1D grid 384: xcd=f%8, i=f/8 (0..47); m=xcd*8+(i&7); n=i>>3 (0..5).
__global__ __launch_bounds__(256) void gemm2_kernel(
    const _Float16* __restrict__ tin, const _Float16* __restrict__ WoT,
    float* __restrict__ out)
{
    __shared__ _Float16 smem[24576];
    TileCtx t = make_ctx();
    const int f = blockIdx.x;
    const int xcd = f & 7, i = f >> 3;
    const int m0 = ((xcd << 3) | (i & 7)) * 128;
    const int n0 = (i >> 3) * 128;

    floatx16 acc[2][2] = {};
    gemm_mainloop_3s32(t, tin + (size_t)m0 * INTER, INTER, WoT + (size_t)n0 * INTER, INTER, INTER, smem, acc);

#pragma unroll
    for (int mt = 0; mt < 2; ++mt) {
#pragma unroll
        for (int nt = 0; nt < 2; ++nt) {
            int col = n0 + t.wn + nt * 32 + t.l31;
#pragma unroll
            for (int reg = 0; reg < 16; ++reg) {
                int row = m0 + t.wm + mt * 32 + (reg & 3) + 8 * (reg >> 2) + 4 * t.half;
                out[(size_t)row * HID + col] = acc[mt][nt][reg];
            }
        }
    }
}

// ---------------------------------------------------------------- launch
extern "C" void kernel_launch(void* const* d_in, const int* in_sizes, int n_in,
                              void* d_out, int out_size, void* d_ws, size_t ws_size,
                              hipStream_t stream) {
    const float* H    = (const float*)d_in[0];
    const float* Wi   = (const float*)d_in[1];
    const float* Wo   = (const float*)d_in[2];
    const float* qg   = (const float*)d_in[3];
    const float* kg   = (const float*)d_in[4];
    const int*   mask = (const int*)d_in[5];
    float* out = (float*)d_out;

    char* base = (char*)d_ws;
    size_t off = 0;
    auto alloc = [&](size_t bytes) { void* p = base + off; off = (off + bytes + 255) & ~(size_t)255; return p; };
    _Float16* Hb   = (_Float16*)alloc((size_t)MROWS * HID * 2);
    _Float16* WiT  = (_Float16*)alloc((size_t)NTOT * HID * 2);
    _Float16* WoT  = (_Float16*)alloc((size_t)HID * INTER * 2);
    _Float16* u    = (_Float16*)alloc((size_t)MROWS * INTER * 2);   // becomes t in-place after pv
    _Float16* vT   = (_Float16*)alloc((size_t)BATCH * INTER * SEQ * 2);
    _Float16* q    = (_Float16*)alloc((size_t)MROWS * DK * 2);
    _Float16* k    = (_Float16*)alloc((size_t)MROWS * DK * 2);
    _Float16* P    = (_Float16*)alloc((size_t)BATCH * SEQ * SEQ * 2);
    float*    scales = (float*)alloc(4 * sizeof(float));

    {
        int n = MROWS * HID;
        cast_h_kernel<<<n / 8 / 256, 256, 0, stream>>>(H, Hb, n);
        trans_wi_kernel<<<dim3(NTOT / 32, HID / 32), dim3(32, 8), 0, stream>>>(Wi, WiT);
        trans_wo_kernel<<<dim3(HID / 32, INTER / 32), dim3(32, 8), 0, stream>>>(Wo, WoT);
        mask_scales_kernel<<<BATCH, 256, 0, stream>>>(mask, scales);
    }
    // GEMM1: M=8192 N=3200 K=768
    gemm1_kernel<<<1600, 256, 0, stream>>>(Hb, WiT, qg, kg, u, vT, q, k);
    // scores + softmax -> P
    scores_kernel<<<512, 256, 0, stream>>>(q, k, mask, scales, P);
    // PV: per batch M=2048 N=1536 K=2048
    pv_kernel<<<768, 256, 0, stream>>>(P, vT, u);
    // GEMM2: M=8192 N=768 K=1536
    gemm2_kernel<<<384, 256, 0, stream>>>(u, WoT, out);
}